// Round 2
// 497.030 us; speedup vs baseline: 1.0489x; 1.0489x over previous
//
#include <hip/hip_runtime.h>
#include <stdint.h>

// ---------------------------------------------------------------------------
// GCN 3-layer forward:  out = A_hat @ relu(A_hat @ relu(A_hat @ x W0 + b0) W1 + b1) W2 + b2
// A_hat = D^-1/2 (A + I) D^-1/2. With pre-scaled rows h'[r] = dinv[r]*h[r]:
//   out[c] = dinv[c] * ( sum_{edges r->c} h'[r] + h'[c] ) + b
//
// R2: agg FETCH == 8 XCD x sizeof(H) (random graph) -> H stored bf16.
// R3: one-shot scatter was 64B-partial-line bound -> bucketed 2-pass sort.
// R4: feature-sliced gather: 16-feat slab (3.2 MB) per XCD L2, slice =
//   blockIdx&7. FETCH 195->60 MB.
// R5: LDS rsqrt LUT (VALU 64->52%), dur flat -> latency-bound.
// R6/R7: NT loads on epk REGRESSED (FETCH +11MB, dur 95->143): epk lines are
//   re-read across unroll blocks; nt evicts them. NT stores kept (write-once).
// R8: revert NT loads; pre-scale H by dinv at GEMM output -> epk is plain src,
//   no LUT, per-edge work = 1 broadcast load + 1 gather + 2 unpack + 2 add.
// R9: counters show nothing saturated (VALU 50%, TA ~30%, HBM 15%) ->
//   latency-bound on per-wave epk->gather chains. Widen slices 16->32 feats:
//   64B rows gathered as uint2 (full line, no half-line waste). Halves chain
//   count (E*4 vs E*8 streams), VMEM instrs, line touches, epk re-reads.
//   Cost: slab 6.4MB vs 4MB L2 (hit ~60%, rest L3). launch_bounds(256,8).
//   (R9 fix: nontemporal_store needs clang ext_vector, not HIP float4.)
// ---------------------------------------------------------------------------

static inline size_t ws_align(size_t x) { return (x + 255) & ~(size_t)255; }

typedef float __f2 __attribute__((ext_vector_type(2)));
typedef float __f4 __attribute__((ext_vector_type(4)));

__device__ __forceinline__ int eidx(const void* p, size_t i, int is64) {
  return is64 ? (int)((const long long*)p)[i] : ((const int*)p)[i];
}

__device__ __forceinline__ uint16_t f2bf(float f) {  // RNE float->bf16
  uint32_t u = __float_as_uint(f);
  u += 0x7fffu + ((u >> 16) & 1u);
  return (uint16_t)(u >> 16);
}
__device__ __forceinline__ float bf_lo(uint32_t h) { return __uint_as_float(h << 16); }
__device__ __forceinline__ float bf_hi(uint32_t h) { return __uint_as_float(h & 0xffff0000u); }

// Detect int64 vs int32 edge_index (little-endian: int64 high words are 0).
__global__ void detect_k(const int* ei, int* flag) {
  if (threadIdx.x == 0 && blockIdx.x == 0) {
    int allz = 1;
    for (int i = 1; i < 128; i += 2)
      if (ei[i] != 0) { allz = 0; break; }
    *flag = allz;
  }
}

// --- passA: bucket histogram via per-block LDS counters --------------------
__global__ __launch_bounds__(256) void passA_k(const void* ei, const int* __restrict__ flag,
                                               int* __restrict__ bucket_cnt, int E, int NB) {
  __shared__ int cnt[256];
  int t = threadIdx.x;
  cnt[t] = 0;
  __syncthreads();
  int is64 = *flag;
  for (int e = blockIdx.x * 256 + t; e < E; e += gridDim.x * 256) {
    int c = eidx(ei, (size_t)E + e, is64);
    atomicAdd(&cnt[c >> 9], 1);
  }
  __syncthreads();
  if (t < NB && cnt[t]) atomicAdd(&bucket_cnt[t], cnt[t]);
}

// --- bscan: exclusive scan of bucket_cnt -> bucket_offs; init gcursor ------
__global__ __launch_bounds__(256) void bscan_k(const int* __restrict__ bucket_cnt,
                                               int* __restrict__ bucket_offs,
                                               int* __restrict__ gcursor, int NB) {
  __shared__ int sh[256];
  int t = threadIdx.x;
  int v = (t < NB) ? bucket_cnt[t] : 0;
  sh[t] = v;
  __syncthreads();
  for (int off = 1; off < 256; off <<= 1) {
    int x = (t >= off) ? sh[t - off] : 0;
    __syncthreads();
    sh[t] += x;
    __syncthreads();
  }
  if (t < NB) {
    int excl = sh[t] - v;
    bucket_offs[t] = excl;
    gcursor[t] = excl;
  }
  if (t == NB - 1) bucket_offs[NB] = sh[t];
}

// --- passB: partition edges into bucket-contiguous epk_binned --------------
__global__ __launch_bounds__(256) void passB_k(const void* ei, const int* __restrict__ flag,
                                               int* __restrict__ gcursor,
                                               int2* __restrict__ epk_binned, int E, int NB) {
  __shared__ int2 sorted[4096];                       // 32 KB
  __shared__ int cnt[256], bbase[256], gb[256], cur[256];
  const int t = threadIdx.x;
  const int base = blockIdx.x * 4096;
  const int CH = min(4096, E - base);
  const int is64 = *flag;

  cnt[t] = 0;
  __syncthreads();
  for (int i = t; i < CH; i += 256) {
    int c = eidx(ei, (size_t)E + base + i, is64);
    atomicAdd(&cnt[c >> 9], 1);
  }
  __syncthreads();
  {
    int v = cnt[t];
    __shared__ int sh[256];
    sh[t] = v;
    __syncthreads();
    for (int off = 1; off < 256; off <<= 1) {
      int x = (t >= off) ? sh[t - off] : 0;
      __syncthreads();
      sh[t] += x;
      __syncthreads();
    }
    bbase[t] = sh[t] - v;
    gb[t] = (t < NB && v) ? atomicAdd(&gcursor[t], v) : 0;
    cur[t] = 0;
  }
  __syncthreads();
  for (int i = t; i < CH; i += 256) {
    int r = eidx(ei, (size_t)base + i, is64);
    int c = eidx(ei, (size_t)E + base + i, is64);
    int b = c >> 9;
    int rank = atomicAdd(&cur[b], 1);
    sorted[bbase[b] + rank] = make_int2(r, c);
  }
  __syncthreads();
  for (int i = t; i < CH; i += 256) {
    int2 v = sorted[i];
    int b = v.y >> 9;
    epk_binned[gb[b] + (i - bbase[b])] = v;
  }
}

// --- passC0: per-bucket degree count -> deg[] and offs[] (coalesced) -------
__global__ __launch_bounds__(256) void passC0_k(const int2* __restrict__ epk_binned,
                                                const int* __restrict__ bucket_offs,
                                                int* __restrict__ deg, int* __restrict__ offs,
                                                int n, int NB) {
  __shared__ int dcnt[512];
  __shared__ int s[256];
  const int t = threadIdx.x;
  const int b = blockIdx.x;
  dcnt[t] = 0; dcnt[t + 256] = 0;
  __syncthreads();
  const int lo = bucket_offs[b], hi = bucket_offs[b + 1];
  for (int i = lo + t; i < hi; i += 256)
    atomicAdd(&dcnt[epk_binned[i].y & 511], 1);
  __syncthreads();
  int d0 = dcnt[2 * t], d1 = dcnt[2 * t + 1];
  int pv = d0 + d1;
  s[t] = pv;
  __syncthreads();
  for (int off = 1; off < 256; off <<= 1) {
    int x = (t >= off) ? s[t - off] : 0;
    __syncthreads();
    s[t] += x;
    __syncthreads();
  }
  int pex = s[t] - pv;
  const int node0 = b << 9;
  int g0 = node0 + 2 * t, g1 = node0 + 2 * t + 1;
  if (g0 < n) { deg[g0] = d0; offs[g0] = lo + pex; }
  if (g1 < n) { deg[g1] = d1; offs[g1] = lo + pex + d0; }
  if (b == NB - 1 && t == 0) offs[n] = hi;
}

__global__ void dinv_k(const int* __restrict__ deg, float* __restrict__ dinv, int n) {
  int i = blockIdx.x * blockDim.x + threadIdx.x;
  if (i < n) dinv[i] = rsqrtf((float)deg[i] + 1.0f);  // +1 = self loop
}

// --- passC: final placement by exact dest; entry = plain src ---------------
__global__ __launch_bounds__(256) void passC_k(const int2* __restrict__ epk_binned,
                                               const int* __restrict__ bucket_offs,
                                               const int* __restrict__ offs,
                                               uint32_t* __restrict__ epk) {
  __shared__ int cur[512];
  const int t = threadIdx.x;
  const int b = blockIdx.x;
  cur[t] = 0; cur[t + 256] = 0;
  __syncthreads();
  const int lo = bucket_offs[b], hi = bucket_offs[b + 1];
  for (int i = lo + t; i < hi; i += 256) {
    int2 v = epk_binned[i];
    int pos = offs[v.y] + atomicAdd(&cur[v.y & 511], 1);
    epk[pos] = (uint32_t)v.x;
  }
}

// --- LDS-tiled SGEMM: Hs (32-feat-sliced bf16) = dinv[row] * (X @ W) -------
// X read dense (layer 0) or 32-feat-sliced fp32 (layers 1/2). Output rows
// pre-scaled by dinv so agg needs no per-edge weight.
// H layout: slice sl (16 uint32 = 32 feats): HW[(sl*N + row)*16 + j],
//   uint32 j within slice holds feats {32*sl + 2j, 32*sl + 2j + 1}.
template <int COLS, bool SLICED_IN>
__global__ __launch_bounds__(256) void gemm_k(const float* __restrict__ X,
                                              const float* __restrict__ W,
                                              const float* __restrict__ dinv,
                                              uint16_t* __restrict__ H, int N) {
  constexpr int KB = 32;
  constexpr int CG = COLS / 8;
  constexpr int RG = 256 / CG;
  constexpr int ROWS = RG * 8;
  constexpr int XP = ROWS + 4;

  __shared__ float Xs[KB][XP];
  __shared__ float Ws[KB][COLS];

  const int tid = threadIdx.x;
  const int cg = tid % CG, rg = tid / CG;
  const int c0 = cg * 8, rr0 = rg * 8;
  const int rowbase = blockIdx.x * ROWS;
  const float4* X4 = (const float4*)X;

  float acc[8][8];
#pragma unroll
  for (int a = 0; a < 8; ++a)
#pragma unroll
    for (int b = 0; b < 8; ++b) acc[a][b] = 0.f;

  for (int k0 = 0; k0 < 128; k0 += KB) {
    __syncthreads();
#pragma unroll
    for (int i = tid; i < KB * (COLS / 4); i += 256) {
      int kk = i / (COLS / 4);
      int cc = i % (COLS / 4);
      float4 w = ((const float4*)(W + (size_t)(k0 + kk) * COLS))[cc];
      ((float4*)&Ws[kk][0])[cc] = w;
    }
#pragma unroll
    for (int i = tid; i < ROWS * (KB / 4); i += 256) {
      int rr = i / (KB / 4);
      int k4 = i % (KB / 4);
      int gr = rowbase + rr;
      if (gr >= N) gr = N - 1;
      float4 xv;
      if (SLICED_IN) {
        int k = k0 + k4 * 4;
        int s = k >> 5, q = (k & 31) >> 2;      // 32-feat slices
        xv = X4[((size_t)s * N + gr) * 8 + q];
      } else {
        xv = X4[(size_t)gr * 32 + (k0 >> 2) + k4];
      }
      Xs[k4 * 4 + 0][rr] = xv.x;
      Xs[k4 * 4 + 1][rr] = xv.y;
      Xs[k4 * 4 + 2][rr] = xv.z;
      Xs[k4 * 4 + 3][rr] = xv.w;
    }
    __syncthreads();
#pragma unroll 2
    for (int k = 0; k < KB; ++k) {
      float4 xa = *(const float4*)&Xs[k][rr0];
      float4 xb = *(const float4*)&Xs[k][rr0 + 4];
      float4 wa = *(const float4*)&Ws[k][c0];
      float4 wb = *(const float4*)&Ws[k][c0 + 4];
      float xr[8] = {xa.x, xa.y, xa.z, xa.w, xb.x, xb.y, xb.z, xb.w};
      float wr[8] = {wa.x, wa.y, wa.z, wa.w, wb.x, wb.y, wb.z, wb.w};
#pragma unroll
      for (int a = 0; a < 8; ++a)
#pragma unroll
        for (int b = 0; b < 8; ++b) acc[a][b] = fmaf(xr[a], wr[b], acc[a][b]);
    }
  }
  uint32_t* HW = (uint32_t*)H;
  const int wbase = c0 >> 1;       // uint32 index within full row
  const int sl = wbase >> 4;       // 32-feat slice (16 uint32)
  const int woff = wbase & 15;
#pragma unroll
  for (int a = 0; a < 8; ++a) {
    int row = rowbase + rr0 + a;
    if (row < N) {
      float sc = dinv[row];
      uint32_t p[4];
#pragma unroll
      for (int q = 0; q < 4; ++q)
        p[q] = (uint32_t)f2bf(sc * acc[a][2 * q]) | ((uint32_t)f2bf(sc * acc[a][2 * q + 1]) << 16);
      uint4 ov = make_uint4(p[0], p[1], p[2], p[3]);
      *(uint4*)&HW[((size_t)sl * N + row) * 16 + woff] = ov;
    }
  }
}

// --- Sliced aggregate, 128 feats: 4 slices x 32 feats. slice = blockIdx&3 --
// (XCD = blockIdx%8 -> XCDs {s, s+4} serve slice s; one 6.4MB slab per XCD.)
// Subgroup of 8 lanes per dest; lane w gathers uint2 = feats 4w..4w+3.
// 8 lanes x 8B = full 64B line per (dest,edge). H pre-scaled by dinv[src].
__global__ __launch_bounds__(256, 8) void agg128s_k(const uint32_t* __restrict__ HW,
                                                    const int* __restrict__ offs,
                                                    const uint32_t* __restrict__ epk,
                                                    const float* __restrict__ bias,
                                                    float* __restrict__ Aout,
                                                    int relu, int N) {
  const int s = blockIdx.x & 3;
  const int g = blockIdx.x >> 2;
  const int lane = threadIdx.x & 63;
  const int wid = threadIdx.x >> 6;
  const int d = lane >> 3, w = lane & 7;
  const int c = g * 32 + wid * 8 + d;
  if (c >= N) return;
  const uint32_t* Hs = HW + (size_t)s * N * 16;
  int e0 = offs[c], e1 = offs[c + 1];
  float a0 = 0.f, a1 = 0.f, a2 = 0.f, a3 = 0.f;
  int e = e0;
  for (; e + 8 <= e1; e += 8) {
    uint32_t p0 = epk[e],     p1 = epk[e + 1], p2 = epk[e + 2], p3 = epk[e + 3];
    uint32_t p4 = epk[e + 4], p5 = epk[e + 5], p6 = epk[e + 6], p7 = epk[e + 7];
    uint2 h0 = *(const uint2*)&Hs[(size_t)p0 * 16 + 2 * w];
    uint2 h1 = *(const uint2*)&Hs[(size_t)p1 * 16 + 2 * w];
    uint2 h2 = *(const uint2*)&Hs[(size_t)p2 * 16 + 2 * w];
    uint2 h3 = *(const uint2*)&Hs[(size_t)p3 * 16 + 2 * w];
    uint2 h4 = *(const uint2*)&Hs[(size_t)p4 * 16 + 2 * w];
    uint2 h5 = *(const uint2*)&Hs[(size_t)p5 * 16 + 2 * w];
    uint2 h6 = *(const uint2*)&Hs[(size_t)p6 * 16 + 2 * w];
    uint2 h7 = *(const uint2*)&Hs[(size_t)p7 * 16 + 2 * w];
    a0 += bf_lo(h0.x); a1 += bf_hi(h0.x); a2 += bf_lo(h0.y); a3 += bf_hi(h0.y);
    a0 += bf_lo(h1.x); a1 += bf_hi(h1.x); a2 += bf_lo(h1.y); a3 += bf_hi(h1.y);
    a0 += bf_lo(h2.x); a1 += bf_hi(h2.x); a2 += bf_lo(h2.y); a3 += bf_hi(h2.y);
    a0 += bf_lo(h3.x); a1 += bf_hi(h3.x); a2 += bf_lo(h3.y); a3 += bf_hi(h3.y);
    a0 += bf_lo(h4.x); a1 += bf_hi(h4.x); a2 += bf_lo(h4.y); a3 += bf_hi(h4.y);
    a0 += bf_lo(h5.x); a1 += bf_hi(h5.x); a2 += bf_lo(h5.y); a3 += bf_hi(h5.y);
    a0 += bf_lo(h6.x); a1 += bf_hi(h6.x); a2 += bf_lo(h6.y); a3 += bf_hi(h6.y);
    a0 += bf_lo(h7.x); a1 += bf_hi(h7.x); a2 += bf_lo(h7.y); a3 += bf_hi(h7.y);
  }
  for (; e + 4 <= e1; e += 4) {
    uint32_t p0 = epk[e], p1 = epk[e + 1], p2 = epk[e + 2], p3 = epk[e + 3];
    uint2 h0 = *(const uint2*)&Hs[(size_t)p0 * 16 + 2 * w];
    uint2 h1 = *(const uint2*)&Hs[(size_t)p1 * 16 + 2 * w];
    uint2 h2 = *(const uint2*)&Hs[(size_t)p2 * 16 + 2 * w];
    uint2 h3 = *(const uint2*)&Hs[(size_t)p3 * 16 + 2 * w];
    a0 += bf_lo(h0.x); a1 += bf_hi(h0.x); a2 += bf_lo(h0.y); a3 += bf_hi(h0.y);
    a0 += bf_lo(h1.x); a1 += bf_hi(h1.x); a2 += bf_lo(h1.y); a3 += bf_hi(h1.y);
    a0 += bf_lo(h2.x); a1 += bf_hi(h2.x); a2 += bf_lo(h2.y); a3 += bf_hi(h2.y);
    a0 += bf_lo(h3.x); a1 += bf_hi(h3.x); a2 += bf_lo(h3.y); a3 += bf_hi(h3.y);
  }
  for (; e < e1; ++e) {
    uint2 h = *(const uint2*)&Hs[(size_t)epk[e] * 16 + 2 * w];
    a0 += bf_lo(h.x); a1 += bf_hi(h.x); a2 += bf_lo(h.y); a3 += bf_hi(h.y);
  }
  float dc = rsqrtf((float)(e1 - e0) + 1.f);
  uint2 hc = *(const uint2*)&Hs[(size_t)c * 16 + 2 * w];
  float r0 = fmaf(dc, a0 + bf_lo(hc.x), bias[s * 32 + 4 * w + 0]);
  float r1 = fmaf(dc, a1 + bf_hi(hc.x), bias[s * 32 + 4 * w + 1]);
  float r2 = fmaf(dc, a2 + bf_lo(hc.y), bias[s * 32 + 4 * w + 2]);
  float r3 = fmaf(dc, a3 + bf_hi(hc.y), bias[s * 32 + 4 * w + 3]);
  if (relu) {
    r0 = fmaxf(r0, 0.f); r1 = fmaxf(r1, 0.f);
    r2 = fmaxf(r2, 0.f); r3 = fmaxf(r3, 0.f);
  }
  __f4 res; res.x = r0; res.y = r1; res.z = r2; res.w = r3;
  __builtin_nontemporal_store(res, (__f4*)(Aout + ((size_t)s * N + c) * 32 + 4 * w));
}

// --- Sliced aggregate, 64 feats: 2 slices x 32 on XCD quads; dense out -----
__global__ __launch_bounds__(256, 8) void agg64s_k(const uint32_t* __restrict__ HW,
                                                   const int* __restrict__ offs,
                                                   const uint32_t* __restrict__ epk,
                                                   const float* __restrict__ bias,
                                                   float* __restrict__ out, int N) {
  const int r = blockIdx.x & 7;
  const int s = r >> 2;          // slice 0..1 (32 feats each)
  const int quar = r & 3;
  const int ng = (N + 31) >> 5;
  const int nq = (ng + 3) >> 2;
  const int g = quar * nq + (blockIdx.x >> 3);
  if (g >= ng) return;
  const int lane = threadIdx.x & 63;
  const int wid = threadIdx.x >> 6;
  const int d = lane >> 3, w = lane & 7;
  const int c = g * 32 + wid * 8 + d;
  if (c >= N) return;
  const uint32_t* Hs = HW + (size_t)s * N * 16;
  int e0 = offs[c], e1 = offs[c + 1];
  float a0 = 0.f, a1 = 0.f, a2 = 0.f, a3 = 0.f;
  int e = e0;
  for (; e + 8 <= e1; e += 8) {
    uint32_t p0 = epk[e],     p1 = epk[e + 1], p2 = epk[e + 2], p3 = epk[e + 3];
    uint32_t p4 = epk[e + 4], p5 = epk[e + 5], p6 = epk[e + 6], p7 = epk[e + 7];
    uint2 h0 = *(const uint2*)&Hs[(size_t)p0 * 16 + 2 * w];
    uint2 h1 = *(const uint2*)&Hs[(size_t)p1 * 16 + 2 * w];
    uint2 h2 = *(const uint2*)&Hs[(size_t)p2 * 16 + 2 * w];
    uint2 h3 = *(const uint2*)&Hs[(size_t)p3 * 16 + 2 * w];
    uint2 h4 = *(const uint2*)&Hs[(size_t)p4 * 16 + 2 * w];
    uint2 h5 = *(const uint2*)&Hs[(size_t)p5 * 16 + 2 * w];
    uint2 h6 = *(const uint2*)&Hs[(size_t)p6 * 16 + 2 * w];
    uint2 h7 = *(const uint2*)&Hs[(size_t)p7 * 16 + 2 * w];
    a0 += bf_lo(h0.x); a1 += bf_hi(h0.x); a2 += bf_lo(h0.y); a3 += bf_hi(h0.y);
    a0 += bf_lo(h1.x); a1 += bf_hi(h1.x); a2 += bf_lo(h1.y); a3 += bf_hi(h1.y);
    a0 += bf_lo(h2.x); a1 += bf_hi(h2.x); a2 += bf_lo(h2.y); a3 += bf_hi(h2.y);
    a0 += bf_lo(h3.x); a1 += bf_hi(h3.x); a2 += bf_lo(h3.y); a3 += bf_hi(h3.y);
    a0 += bf_lo(h4.x); a1 += bf_hi(h4.x); a2 += bf_lo(h4.y); a3 += bf_hi(h4.y);
    a0 += bf_lo(h5.x); a1 += bf_hi(h5.x); a2 += bf_lo(h5.y); a3 += bf_hi(h5.y);
    a0 += bf_lo(h6.x); a1 += bf_hi(h6.x); a2 += bf_lo(h6.y); a3 += bf_hi(h6.y);
    a0 += bf_lo(h7.x); a1 += bf_hi(h7.x); a2 += bf_lo(h7.y); a3 += bf_hi(h7.y);
  }
  for (; e + 4 <= e1; e += 4) {
    uint32_t p0 = epk[e], p1 = epk[e + 1], p2 = epk[e + 2], p3 = epk[e + 3];
    uint2 h0 = *(const uint2*)&Hs[(size_t)p0 * 16 + 2 * w];
    uint2 h1 = *(const uint2*)&Hs[(size_t)p1 * 16 + 2 * w];
    uint2 h2 = *(const uint2*)&Hs[(size_t)p2 * 16 + 2 * w];
    uint2 h3 = *(const uint2*)&Hs[(size_t)p3 * 16 + 2 * w];
    a0 += bf_lo(h0.x); a1 += bf_hi(h0.x); a2 += bf_lo(h0.y); a3 += bf_hi(h0.y);
    a0 += bf_lo(h1.x); a1 += bf_hi(h1.x); a2 += bf_lo(h1.y); a3 += bf_hi(h1.y);
    a0 += bf_lo(h2.x); a1 += bf_hi(h2.x); a2 += bf_lo(h2.y); a3 += bf_hi(h2.y);
    a0 += bf_lo(h3.x); a1 += bf_hi(h3.x); a2 += bf_lo(h3.y); a3 += bf_hi(h3.y);
  }
  for (; e < e1; ++e) {
    uint2 h = *(const uint2*)&Hs[(size_t)epk[e] * 16 + 2 * w];
    a0 += bf_lo(h.x); a1 += bf_hi(h.x); a2 += bf_lo(h.y); a3 += bf_hi(h.y);
  }
  float dc = rsqrtf((float)(e1 - e0) + 1.f);
  uint2 hc = *(const uint2*)&Hs[(size_t)c * 16 + 2 * w];
  float r0 = fmaf(dc, a0 + bf_lo(hc.x), bias[s * 32 + 4 * w + 0]);
  float r1 = fmaf(dc, a1 + bf_hi(hc.x), bias[s * 32 + 4 * w + 1]);
  float r2 = fmaf(dc, a2 + bf_lo(hc.y), bias[s * 32 + 4 * w + 2]);
  float r3 = fmaf(dc, a3 + bf_hi(hc.y), bias[s * 32 + 4 * w + 3]);
  __f4 res; res.x = r0; res.y = r1; res.z = r2; res.w = r3;
  __builtin_nontemporal_store(res, (__f4*)(out + (size_t)c * 64 + s * 32 + 4 * w));
}

extern "C" void kernel_launch(void* const* d_in, const int* in_sizes, int n_in,
                              void* d_out, int out_size, void* d_ws, size_t ws_size,
                              hipStream_t stream) {
  const float* x  = (const float*)d_in[0];
  const void*  ei = d_in[1];
  const float* W0 = (const float*)d_in[2];
  const float* b0 = (const float*)d_in[3];
  const float* W1 = (const float*)d_in[4];
  const float* b1 = (const float*)d_in[5];
  const float* W2 = (const float*)d_in[6];
  const float* b2 = (const float*)d_in[7];
  float* out = (float*)d_out;

  const int n = in_sizes[0] / 128;   // 100000
  const int E = in_sizes[1] / 2;     // 1600000
  const int NB = (n + 511) >> 9;     // buckets of 512 dests (NB <= 256)

  char* ws = (char*)d_ws;
  size_t off = 0;
  auto alloc = [&](size_t bytes) { char* p = ws + off; off = ws_align(off + bytes); return p; };
  int*      bucket_cnt  = (int*)alloc(256 * 4);
  int*      bucket_offs = (int*)alloc(257 * 4);
  int*      gcursor     = (int*)alloc(256 * 4);
  int*      deg         = (int*)alloc((size_t)n * 4);
  int*      offs        = (int*)alloc((size_t)(n + 1) * 4);
  float*    dinv        = (float*)alloc((size_t)n * 4);
  int*      flag        = (int*)alloc(4);
  int2*     epk_binned  = (int2*)alloc((size_t)E * 8);
  uint32_t* epk         = (uint32_t*)alloc((size_t)E * 4);
  uint16_t* hbuf        = (uint16_t*)alloc((size_t)n * 128 * 2);  // sliced bf16 H'
  float*    abuf        = (float*)alloc((size_t)n * 128 * 4);     // sliced fp32 acts
  (void)ws_size;

  hipMemsetAsync(bucket_cnt, 0, 256 * 4, stream);

  detect_k<<<1, 64, 0, stream>>>((const int*)ei, flag);
  passA_k<<<512, 256, 0, stream>>>(ei, flag, bucket_cnt, E, NB);
  bscan_k<<<1, 256, 0, stream>>>(bucket_cnt, bucket_offs, gcursor, NB);
  passB_k<<<(E + 4095) / 4096, 256, 0, stream>>>(ei, flag, gcursor, epk_binned, E, NB);
  passC0_k<<<NB, 256, 0, stream>>>(epk_binned, bucket_offs, deg, offs, n, NB);
  dinv_k<<<(n + 255) / 256, 256, 0, stream>>>(deg, dinv, n);
  passC_k<<<NB, 256, 0, stream>>>(epk_binned, bucket_offs, offs, epk);

  const int agg128_blocks = 4 * ((n + 31) / 32);
  const int ng = (n + 31) >> 5, nq = (ng + 3) >> 2;
  const int agg64_blocks = 8 * nq;

  // Layer 0 (dense x input)
  gemm_k<128, false><<<(n + 127) / 128, 256, 0, stream>>>(x, W0, dinv, hbuf, n);
  agg128s_k<<<agg128_blocks, 256, 0, stream>>>((const uint32_t*)hbuf, offs, epk, b0, abuf, 1, n);
  // Layer 1 (sliced activations)
  gemm_k<128, true><<<(n + 127) / 128, 256, 0, stream>>>(abuf, W1, dinv, hbuf, n);
  agg128s_k<<<agg128_blocks, 256, 0, stream>>>((const uint32_t*)hbuf, offs, epk, b1, abuf, 1, n);
  // Layer 2 (no relu) -> d_out dense fp32
  gemm_k<64, true><<<(n + 255) / 256, 256, 0, stream>>>(abuf, W2, dinv, hbuf, n);
  agg64s_k<<<agg64_blocks, 256, 0, stream>>>((const uint32_t*)hbuf, offs, epk, b2, out, n);
}

// Round 3
// 434.279 us; speedup vs baseline: 1.2005x; 1.1445x over previous
//
#include <hip/hip_runtime.h>
#include <stdint.h>

// ---------------------------------------------------------------------------
// GCN 3-layer forward:  out = A_hat @ relu(A_hat @ relu(A_hat @ x W0 + b0) W1 + b1) W2 + b2
// A_hat = D^-1/2 (A + I) D^-1/2. With pre-scaled rows h'[r] = dinv[r]*h[r]:
//   out[c] = dinv[c] * ( sum_{edges r->c} h'[r] + h'[c] ) + b
//
// R2: agg FETCH == 8 XCD x sizeof(H) (random graph) -> H stored bf16.
// R3: one-shot scatter was 64B-partial-line bound -> bucketed 2-pass sort.
// R4: feature-sliced gather: slice slab per XCD L2. FETCH 195->60 MB.
// R8: pre-scale H by dinv at GEMM output -> agg per-edge work = gather+add.
// R9: 32-feat slices, uint2 gathers (full 64B line), halved chain count.
//   agg128 82 -> ~60us. 497 total. gemm_k (fp32 vector, 46TF, MfmaUtil=0)
//   is now the top kernel at ~70us each.
// R10: MFMA gemm. fp32 accuracy via 3-term bf16 split (Ah*Bh+Al*Bh+Ah*Bl,
//   err ~2^-18). W pre-split+fragment-packed once into global (wprep_k),
//   read L2-cached lane-contiguous, no unpack. X staged per 32-k chunk into
//   16KB LDS as packed (hi|lo) uint32, k-word XOR swizzle (k ^= (row&7)<<2)
//   to kill 16-way A-frag ds_read conflicts. mfma_f32_16x16x32_bf16,
//   D: col=lane&15, row=(lane>>4)*4+reg. Epilogue pairs cols via shfl_xor
//   so sliced-bf16 H layout is unchanged for agg. absmax must stay 2^-9.
// ---------------------------------------------------------------------------

static inline size_t ws_align(size_t x) { return (x + 255) & ~(size_t)255; }

typedef float __f2 __attribute__((ext_vector_type(2)));
typedef float __f4 __attribute__((ext_vector_type(4)));
typedef __attribute__((ext_vector_type(8))) short short8v;
typedef __attribute__((ext_vector_type(4))) float f32x4;

__device__ __forceinline__ int eidx(const void* p, size_t i, int is64) {
  return is64 ? (int)((const long long*)p)[i] : ((const int*)p)[i];
}

__device__ __forceinline__ uint16_t f2bf(float f) {  // RNE float->bf16
  uint32_t u = __float_as_uint(f);
  u += 0x7fffu + ((u >> 16) & 1u);
  return (uint16_t)(u >> 16);
}
__device__ __forceinline__ float bf_lo(uint32_t h) { return __uint_as_float(h << 16); }
__device__ __forceinline__ float bf_hi(uint32_t h) { return __uint_as_float(h & 0xffff0000u); }

// Detect int64 vs int32 edge_index (little-endian: int64 high words are 0).
__global__ void detect_k(const int* ei, int* flag) {
  if (threadIdx.x == 0 && blockIdx.x == 0) {
    int allz = 1;
    for (int i = 1; i < 128; i += 2)
      if (ei[i] != 0) { allz = 0; break; }
    *flag = allz;
  }
}

// --- passA: bucket histogram via per-block LDS counters --------------------
__global__ __launch_bounds__(256) void passA_k(const void* ei, const int* __restrict__ flag,
                                               int* __restrict__ bucket_cnt, int E, int NB) {
  __shared__ int cnt[256];
  int t = threadIdx.x;
  cnt[t] = 0;
  __syncthreads();
  int is64 = *flag;
  for (int e = blockIdx.x * 256 + t; e < E; e += gridDim.x * 256) {
    int c = eidx(ei, (size_t)E + e, is64);
    atomicAdd(&cnt[c >> 9], 1);
  }
  __syncthreads();
  if (t < NB && cnt[t]) atomicAdd(&bucket_cnt[t], cnt[t]);
}

// --- bscan: exclusive scan of bucket_cnt -> bucket_offs; init gcursor ------
__global__ __launch_bounds__(256) void bscan_k(const int* __restrict__ bucket_cnt,
                                               int* __restrict__ bucket_offs,
                                               int* __restrict__ gcursor, int NB) {
  __shared__ int sh[256];
  int t = threadIdx.x;
  int v = (t < NB) ? bucket_cnt[t] : 0;
  sh[t] = v;
  __syncthreads();
  for (int off = 1; off < 256; off <<= 1) {
    int x = (t >= off) ? sh[t - off] : 0;
    __syncthreads();
    sh[t] += x;
    __syncthreads();
  }
  if (t < NB) {
    int excl = sh[t] - v;
    bucket_offs[t] = excl;
    gcursor[t] = excl;
  }
  if (t == NB - 1) bucket_offs[NB] = sh[t];
}

// --- passB: partition edges into bucket-contiguous epk_binned --------------
__global__ __launch_bounds__(256) void passB_k(const void* ei, const int* __restrict__ flag,
                                               int* __restrict__ gcursor,
                                               int2* __restrict__ epk_binned, int E, int NB) {
  __shared__ int2 sorted[4096];                       // 32 KB
  __shared__ int cnt[256], bbase[256], gb[256], cur[256];
  const int t = threadIdx.x;
  const int base = blockIdx.x * 4096;
  const int CH = min(4096, E - base);
  const int is64 = *flag;

  cnt[t] = 0;
  __syncthreads();
  for (int i = t; i < CH; i += 256) {
    int c = eidx(ei, (size_t)E + base + i, is64);
    atomicAdd(&cnt[c >> 9], 1);
  }
  __syncthreads();
  {
    int v = cnt[t];
    __shared__ int sh[256];
    sh[t] = v;
    __syncthreads();
    for (int off = 1; off < 256; off <<= 1) {
      int x = (t >= off) ? sh[t - off] : 0;
      __syncthreads();
      sh[t] += x;
      __syncthreads();
    }
    bbase[t] = sh[t] - v;
    gb[t] = (t < NB && v) ? atomicAdd(&gcursor[t], v) : 0;
    cur[t] = 0;
  }
  __syncthreads();
  for (int i = t; i < CH; i += 256) {
    int r = eidx(ei, (size_t)base + i, is64);
    int c = eidx(ei, (size_t)E + base + i, is64);
    int b = c >> 9;
    int rank = atomicAdd(&cur[b], 1);
    sorted[bbase[b] + rank] = make_int2(r, c);
  }
  __syncthreads();
  for (int i = t; i < CH; i += 256) {
    int2 v = sorted[i];
    int b = v.y >> 9;
    epk_binned[gb[b] + (i - bbase[b])] = v;
  }
}

// --- passC0: per-bucket degree count -> deg[] and offs[] (coalesced) -------
__global__ __launch_bounds__(256) void passC0_k(const int2* __restrict__ epk_binned,
                                                const int* __restrict__ bucket_offs,
                                                int* __restrict__ deg, int* __restrict__ offs,
                                                int n, int NB) {
  __shared__ int dcnt[512];
  __shared__ int s[256];
  const int t = threadIdx.x;
  const int b = blockIdx.x;
  dcnt[t] = 0; dcnt[t + 256] = 0;
  __syncthreads();
  const int lo = bucket_offs[b], hi = bucket_offs[b + 1];
  for (int i = lo + t; i < hi; i += 256)
    atomicAdd(&dcnt[epk_binned[i].y & 511], 1);
  __syncthreads();
  int d0 = dcnt[2 * t], d1 = dcnt[2 * t + 1];
  int pv = d0 + d1;
  s[t] = pv;
  __syncthreads();
  for (int off = 1; off < 256; off <<= 1) {
    int x = (t >= off) ? s[t - off] : 0;
    __syncthreads();
    s[t] += x;
    __syncthreads();
  }
  int pex = s[t] - pv;
  const int node0 = b << 9;
  int g0 = node0 + 2 * t, g1 = node0 + 2 * t + 1;
  if (g0 < n) { deg[g0] = d0; offs[g0] = lo + pex; }
  if (g1 < n) { deg[g1] = d1; offs[g1] = lo + pex + d0; }
  if (b == NB - 1 && t == 0) offs[n] = hi;
}

__global__ void dinv_k(const int* __restrict__ deg, float* __restrict__ dinv, int n) {
  int i = blockIdx.x * blockDim.x + threadIdx.x;
  if (i < n) dinv[i] = rsqrtf((float)deg[i] + 1.0f);  // +1 = self loop
}

// --- passC: final placement by exact dest; entry = plain src ---------------
__global__ __launch_bounds__(256) void passC_k(const int2* __restrict__ epk_binned,
                                               const int* __restrict__ bucket_offs,
                                               const int* __restrict__ offs,
                                               uint32_t* __restrict__ epk) {
  __shared__ int cur[512];
  const int t = threadIdx.x;
  const int b = blockIdx.x;
  cur[t] = 0; cur[t + 256] = 0;
  __syncthreads();
  const int lo = bucket_offs[b], hi = bucket_offs[b + 1];
  for (int i = lo + t; i < hi; i += 256) {
    int2 v = epk_binned[i];
    int pos = offs[v.y] + atomicAdd(&cur[v.y & 511], 1);
    epk[pos] = (uint32_t)v.x;
  }
}

// --- wprep: split W fp32 -> bf16 hi/lo MFMA fragments in global ------------
// Frag f = kc*CT + ct (kc = 32-k chunk, ct = 16-col tile). Per frag 1024 u16:
//   [l*8 + j]        = hi bf16 of W[kc*32 + (l>>4)*8 + j][ct*16 + (l&15)]
//   [512 + l*8 + j]  = lo bf16 (residual)
template <int COLS>
__global__ void wprep_k(const float* __restrict__ W, uint16_t* __restrict__ Wf) {
  constexpr int CT = COLS / 16;
  const int f = blockIdx.x;  // [0, 4*CT)
  const int kc = f / CT, ct = f % CT;
  const int l = threadIdx.x;  // 0..63
#pragma unroll
  for (int j = 0; j < 8; ++j) {
    int k = kc * 32 + (l >> 4) * 8 + j;
    int col = ct * 16 + (l & 15);
    float wv = W[(size_t)k * COLS + col];
    uint16_t hi = f2bf(wv);
    float res = wv - __uint_as_float((uint32_t)hi << 16);
    Wf[(size_t)f * 1024 + l * 8 + j] = hi;
    Wf[(size_t)f * 1024 + 512 + l * 8 + j] = f2bf(res);
  }
}

// --- MFMA GEMM: Hs (32-feat-sliced bf16) = dinv[row] * (X @ W) -------------
// 3-term bf16 split for fp32 accuracy. BM=128, 4 waves x 32 rows.
// X staged per 32-k chunk into LDS as packed (hi<<16|lo) uint32 with k-word
// XOR swizzle (k' = k ^ ((row&7)<<2)) -> conflict-free A-frag ds_read_b128.
// B frags read straight from global Wf (L2-resident, lane-contiguous).
template <int COLS, bool SLICED_IN>
__global__ __launch_bounds__(256) void gemm_k(const float* __restrict__ X,
                                              const uint16_t* __restrict__ Wf,
                                              const float* __restrict__ dinv,
                                              uint16_t* __restrict__ H, int N) {
  constexpr int CT = COLS / 16;
  __shared__ uint32_t Xp[128 * 32];  // 16 KB

  const int tid = threadIdx.x;
  const int l = tid & 63, w = tid >> 6;
  const int rowbase = blockIdx.x * 128;
  const float4* X4 = (const float4*)X;

  f32x4 acc[2][CT];
#pragma unroll
  for (int rt = 0; rt < 2; ++rt)
#pragma unroll
    for (int ct = 0; ct < CT; ++ct) acc[rt][ct] = (f32x4)0.f;

  for (int kc = 0; kc < 4; ++kc) {
    __syncthreads();
    // stage X chunk: 128 rows x 32 k, packed bf16 hi/lo, swizzled
#pragma unroll
    for (int t = 0; t < 4; ++t) {
      int i = tid + t * 256;  // 0..1023
      int r = i >> 3, q = i & 7;
      int gr = rowbase + r;
      if (gr >= N) gr = N - 1;
      float4 xv = SLICED_IN ? X4[((size_t)kc * N + gr) * 8 + q]
                            : X4[(size_t)gr * 32 + kc * 8 + q];
      float xs[4] = {xv.x, xv.y, xv.z, xv.w};
      uint32_t p[4];
#pragma unroll
      for (int e = 0; e < 4; ++e) {
        uint16_t hi = f2bf(xs[e]);
        float res = xs[e] - __uint_as_float((uint32_t)hi << 16);
        p[e] = ((uint32_t)hi << 16) | (uint32_t)f2bf(res);
      }
      int blk = q ^ (r & 7);
      *(uint4*)&Xp[r * 32 + blk * 4] = make_uint4(p[0], p[1], p[2], p[3]);
    }
    __syncthreads();

    // A fragments (2 row-tiles), unpack hi/lo via v_perm
    short8v ah[2], al[2];
#pragma unroll
    for (int rt = 0; rt < 2; ++rt) {
      int r = w * 32 + rt * 16 + (l & 15);
      int c = (r & 7) << 2;
      int b0 = ((l >> 4) * 8) ^ c;
      int b1 = ((l >> 4) * 8 + 4) ^ c;
      uint32_t ua[8];
      *(uint4*)&ua[0] = *(const uint4*)&Xp[r * 32 + b0];
      *(uint4*)&ua[4] = *(const uint4*)&Xp[r * 32 + b1];
      union { uint32_t d[4]; short8v v; } ch, cl;
#pragma unroll
      for (int p2 = 0; p2 < 4; ++p2) {
        ch.d[p2] = __builtin_amdgcn_perm(ua[2 * p2 + 1], ua[2 * p2], 0x07060302u);
        cl.d[p2] = __builtin_amdgcn_perm(ua[2 * p2 + 1], ua[2 * p2], 0x05040100u);
      }
      ah[rt] = ch.v;
      al[rt] = cl.v;
    }

    // B fragments from global (L2), 3-term mfma
#pragma unroll
    for (int ct = 0; ct < CT; ++ct) {
      size_t fo = (size_t)(kc * CT + ct) * 1024;
      short8v bh = *(const short8v*)(Wf + fo + l * 8);
      short8v bl = *(const short8v*)(Wf + fo + 512 + l * 8);
#pragma unroll
      for (int rt = 0; rt < 2; ++rt) {
        acc[rt][ct] = __builtin_amdgcn_mfma_f32_16x16x32_bf16(ah[rt], bh, acc[rt][ct], 0, 0, 0);
        acc[rt][ct] = __builtin_amdgcn_mfma_f32_16x16x32_bf16(al[rt], bh, acc[rt][ct], 0, 0, 0);
        acc[rt][ct] = __builtin_amdgcn_mfma_f32_16x16x32_bf16(ah[rt], bl, acc[rt][ct], 0, 0, 0);
      }
    }
  }

  // Epilogue: D col=lane&15, row=(lane>>4)*4+reg. Pair even/odd cols via
  // shfl_xor -> uint32 words, sliced-bf16 H layout (same as agg expects).
  uint32_t* HW = (uint32_t*)H;
  const int lq = l >> 4, lc = l & 15;
#pragma unroll
  for (int rt = 0; rt < 2; ++rt) {
#pragma unroll
    for (int q = 0; q < 4; ++q) {
      int row = rowbase + w * 32 + rt * 16 + lq * 4 + q;
      bool ok = row < N;
      float dv = ok ? dinv[row] : 0.f;
#pragma unroll
      for (int ct = 0; ct < CT; ++ct) {
        float v = acc[rt][ct][q] * dv;
        int b = (int)f2bf(v);
        int other = __shfl_xor(b, 1);
        if (ok && !(l & 1)) {
          uint32_t word = (uint32_t)b | ((uint32_t)other << 16);
          HW[((size_t)(ct >> 1) * N + row) * 16 + (ct & 1) * 8 + (lc >> 1)] = word;
        }
      }
    }
  }
}

// --- Sliced aggregate, 128 feats: 4 slices x 32 feats. slice = blockIdx&3 --
__global__ __launch_bounds__(256, 8) void agg128s_k(const uint32_t* __restrict__ HW,
                                                    const int* __restrict__ offs,
                                                    const uint32_t* __restrict__ epk,
                                                    const float* __restrict__ bias,
                                                    float* __restrict__ Aout,
                                                    int relu, int N) {
  const int s = blockIdx.x & 3;
  const int g = blockIdx.x >> 2;
  const int lane = threadIdx.x & 63;
  const int wid = threadIdx.x >> 6;
  const int d = lane >> 3, w = lane & 7;
  const int c = g * 32 + wid * 8 + d;
  if (c >= N) return;
  const uint32_t* Hs = HW + (size_t)s * N * 16;
  int e0 = offs[c], e1 = offs[c + 1];
  float a0 = 0.f, a1 = 0.f, a2 = 0.f, a3 = 0.f;
  int e = e0;
  for (; e + 8 <= e1; e += 8) {
    uint32_t p0 = epk[e],     p1 = epk[e + 1], p2 = epk[e + 2], p3 = epk[e + 3];
    uint32_t p4 = epk[e + 4], p5 = epk[e + 5], p6 = epk[e + 6], p7 = epk[e + 7];
    uint2 h0 = *(const uint2*)&Hs[(size_t)p0 * 16 + 2 * w];
    uint2 h1 = *(const uint2*)&Hs[(size_t)p1 * 16 + 2 * w];
    uint2 h2 = *(const uint2*)&Hs[(size_t)p2 * 16 + 2 * w];
    uint2 h3 = *(const uint2*)&Hs[(size_t)p3 * 16 + 2 * w];
    uint2 h4 = *(const uint2*)&Hs[(size_t)p4 * 16 + 2 * w];
    uint2 h5 = *(const uint2*)&Hs[(size_t)p5 * 16 + 2 * w];
    uint2 h6 = *(const uint2*)&Hs[(size_t)p6 * 16 + 2 * w];
    uint2 h7 = *(const uint2*)&Hs[(size_t)p7 * 16 + 2 * w];
    a0 += bf_lo(h0.x); a1 += bf_hi(h0.x); a2 += bf_lo(h0.y); a3 += bf_hi(h0.y);
    a0 += bf_lo(h1.x); a1 += bf_hi(h1.x); a2 += bf_lo(h1.y); a3 += bf_hi(h1.y);
    a0 += bf_lo(h2.x); a1 += bf_hi(h2.x); a2 += bf_lo(h2.y); a3 += bf_hi(h2.y);
    a0 += bf_lo(h3.x); a1 += bf_hi(h3.x); a2 += bf_lo(h3.y); a3 += bf_hi(h3.y);
    a0 += bf_lo(h4.x); a1 += bf_hi(h4.x); a2 += bf_lo(h4.y); a3 += bf_hi(h4.y);
    a0 += bf_lo(h5.x); a1 += bf_hi(h5.x); a2 += bf_lo(h5.y); a3 += bf_hi(h5.y);
    a0 += bf_lo(h6.x); a1 += bf_hi(h6.x); a2 += bf_lo(h6.y); a3 += bf_hi(h6.y);
    a0 += bf_lo(h7.x); a1 += bf_hi(h7.x); a2 += bf_lo(h7.y); a3 += bf_hi(h7.y);
  }
  for (; e + 4 <= e1; e += 4) {
    uint32_t p0 = epk[e], p1 = epk[e + 1], p2 = epk[e + 2], p3 = epk[e + 3];
    uint2 h0 = *(const uint2*)&Hs[(size_t)p0 * 16 + 2 * w];
    uint2 h1 = *(const uint2*)&Hs[(size_t)p1 * 16 + 2 * w];
    uint2 h2 = *(const uint2*)&Hs[(size_t)p2 * 16 + 2 * w];
    uint2 h3 = *(const uint2*)&Hs[(size_t)p3 * 16 + 2 * w];
    a0 += bf_lo(h0.x); a1 += bf_hi(h0.x); a2 += bf_lo(h0.y); a3 += bf_hi(h0.y);
    a0 += bf_lo(h1.x); a1 += bf_hi(h1.x); a2 += bf_lo(h1.y); a3 += bf_hi(h1.y);
    a0 += bf_lo(h2.x); a1 += bf_hi(h2.x); a2 += bf_lo(h2.y); a3 += bf_hi(h2.y);
    a0 += bf_lo(h3.x); a1 += bf_hi(h3.x); a2 += bf_lo(h3.y); a3 += bf_hi(h3.y);
  }
  for (; e < e1; ++e) {
    uint2 h = *(const uint2*)&Hs[(size_t)epk[e] * 16 + 2 * w];
    a0 += bf_lo(h.x); a1 += bf_hi(h.x); a2 += bf_lo(h.y); a3 += bf_hi(h.y);
  }
  float dc = rsqrtf((float)(e1 - e0) + 1.f);
  uint2 hc = *(const uint2*)&Hs[(size_t)c * 16 + 2 * w];
  float r0 = fmaf(dc, a0 + bf_lo(hc.x), bias[s * 32 + 4 * w + 0]);
  float r1 = fmaf(dc, a1 + bf_hi(hc.x), bias[s * 32 + 4 * w + 1]);
  float r2 = fmaf(dc, a2 + bf_lo(hc.y), bias[s * 32 + 4 * w + 2]);
  float r3 = fmaf(dc, a3 + bf_hi(hc.y), bias[s * 32 + 4 * w + 3]);
  if (relu) {
    r0 = fmaxf(r0, 0.f); r1 = fmaxf(r1, 0.f);
    r2 = fmaxf(r2, 0.f); r3 = fmaxf(r3, 0.f);
  }
  __f4 res; res.x = r0; res.y = r1; res.z = r2; res.w = r3;
  __builtin_nontemporal_store(res, (__f4*)(Aout + ((size_t)s * N + c) * 32 + 4 * w));
}

// --- Sliced aggregate, 64 feats: 2 slices x 32 on XCD quads; dense out -----
__global__ __launch_bounds__(256, 8) void agg64s_k(const uint32_t* __restrict__ HW,
                                                   const int* __restrict__ offs,
                                                   const uint32_t* __restrict__ epk,
                                                   const float* __restrict__ bias,
                                                   float* __restrict__ out, int N) {
  const int r = blockIdx.x & 7;
  const int s = r >> 2;          // slice 0..1 (32 feats each)
  const int quar = r & 3;
  const int ng = (N + 31) >> 5;
  const int nq = (ng + 3) >> 2;
  const int g = quar * nq + (blockIdx.x >> 3);
  if (g >= ng) return;
  const int lane = threadIdx.x & 63;
  const int wid = threadIdx.x >> 6;
  const int d = lane >> 3, w = lane & 7;
  const int c = g * 32 + wid * 8 + d;
  if (c >= N) return;
  const uint32_t* Hs = HW + (size_t)s * N * 16;
  int e0 = offs[c], e1 = offs[c + 1];
  float a0 = 0.f, a1 = 0.f, a2 = 0.f, a3 = 0.f;
  int e = e0;
  for (; e + 8 <= e1; e += 8) {
    uint32_t p0 = epk[e],     p1 = epk[e + 1], p2 = epk[e + 2], p3 = epk[e + 3];
    uint32_t p4 = epk[e + 4], p5 = epk[e + 5], p6 = epk[e + 6], p7 = epk[e + 7];
    uint2 h0 = *(const uint2*)&Hs[(size_t)p0 * 16 + 2 * w];
    uint2 h1 = *(const uint2*)&Hs[(size_t)p1 * 16 + 2 * w];
    uint2 h2 = *(const uint2*)&Hs[(size_t)p2 * 16 + 2 * w];
    uint2 h3 = *(const uint2*)&Hs[(size_t)p3 * 16 + 2 * w];
    uint2 h4 = *(const uint2*)&Hs[(size_t)p4 * 16 + 2 * w];
    uint2 h5 = *(const uint2*)&Hs[(size_t)p5 * 16 + 2 * w];
    uint2 h6 = *(const uint2*)&Hs[(size_t)p6 * 16 + 2 * w];
    uint2 h7 = *(const uint2*)&Hs[(size_t)p7 * 16 + 2 * w];
    a0 += bf_lo(h0.x); a1 += bf_hi(h0.x); a2 += bf_lo(h0.y); a3 += bf_hi(h0.y);
    a0 += bf_lo(h1.x); a1 += bf_hi(h1.x); a2 += bf_lo(h1.y); a3 += bf_hi(h1.y);
    a0 += bf_lo(h2.x); a1 += bf_hi(h2.x); a2 += bf_lo(h2.y); a3 += bf_hi(h2.y);
    a0 += bf_lo(h3.x); a1 += bf_hi(h3.x); a2 += bf_lo(h3.y); a3 += bf_hi(h3.y);
    a0 += bf_lo(h4.x); a1 += bf_hi(h4.x); a2 += bf_lo(h4.y); a3 += bf_hi(h4.y);
    a0 += bf_lo(h5.x); a1 += bf_hi(h5.x); a2 += bf_lo(h5.y); a3 += bf_hi(h5.y);
    a0 += bf_lo(h6.x); a1 += bf_hi(h6.x); a2 += bf_lo(h6.y); a3 += bf_hi(h6.y);
    a0 += bf_lo(h7.x); a1 += bf_hi(h7.x); a2 += bf_lo(h7.y); a3 += bf_hi(h7.y);
  }
  for (; e + 4 <= e1; e += 4) {
    uint32_t p0 = epk[e], p1 = epk[e + 1], p2 = epk[e + 2], p3 = epk[e + 3];
    uint2 h0 = *(const uint2*)&Hs[(size_t)p0 * 16 + 2 * w];
    uint2 h1 = *(const uint2*)&Hs[(size_t)p1 * 16 + 2 * w];
    uint2 h2 = *(const uint2*)&Hs[(size_t)p2 * 16 + 2 * w];
    uint2 h3 = *(const uint2*)&Hs[(size_t)p3 * 16 + 2 * w];
    a0 += bf_lo(h0.x); a1 += bf_hi(h0.x); a2 += bf_lo(h0.y); a3 += bf_hi(h0.y);
    a0 += bf_lo(h1.x); a1 += bf_hi(h1.x); a2 += bf_lo(h1.y); a3 += bf_hi(h1.y);
    a0 += bf_lo(h2.x); a1 += bf_hi(h2.x); a2 += bf_lo(h2.y); a3 += bf_hi(h2.y);
    a0 += bf_lo(h3.x); a1 += bf_hi(h3.x); a2 += bf_lo(h3.y); a3 += bf_hi(h3.y);
  }
  for (; e < e1; ++e) {
    uint2 h = *(const uint2*)&Hs[(size_t)epk[e] * 16 + 2 * w];
    a0 += bf_lo(h.x); a1 += bf_hi(h.x); a2 += bf_lo(h.y); a3 += bf_hi(h.y);
  }
  float dc = rsqrtf((float)(e1 - e0) + 1.f);
  uint2 hc = *(const uint2*)&Hs[(size_t)c * 16 + 2 * w];
  float r0 = fmaf(dc, a0 + bf_lo(hc.x), bias[s * 32 + 4 * w + 0]);
  float r1 = fmaf(dc, a1 + bf_hi(hc.x), bias[s * 32 + 4 * w + 1]);
  float r2 = fmaf(dc, a2 + bf_lo(hc.y), bias[s * 32 + 4 * w + 2]);
  float r3 = fmaf(dc, a3 + bf_hi(hc.y), bias[s * 32 + 4 * w + 3]);
  __f4 res; res.x = r0; res.y = r1; res.z = r2; res.w = r3;
  __builtin_nontemporal_store(res, (__f4*)(out + (size_t)c * 64 + s * 32 + 4 * w));
}

extern "C" void kernel_launch(void* const* d_in, const int* in_sizes, int n_in,
                              void* d_out, int out_size, void* d_ws, size_t ws_size,
                              hipStream_t stream) {
  const float* x  = (const float*)d_in[0];
  const void*  ei = d_in[1];
  const float* W0 = (const float*)d_in[2];
  const float* b0 = (const float*)d_in[3];
  const float* W1 = (const float*)d_in[4];
  const float* b1 = (const float*)d_in[5];
  const float* W2 = (const float*)d_in[6];
  const float* b2 = (const float*)d_in[7];
  float* out = (float*)d_out;

  const int n = in_sizes[0] / 128;   // 100000
  const int E = in_sizes[1] / 2;     // 1600000
  const int NB = (n + 511) >> 9;     // buckets of 512 dests (NB <= 256)

  char* ws = (char*)d_ws;
  size_t off = 0;
  auto alloc = [&](size_t bytes) { char* p = ws + off; off = ws_align(off + bytes); return p; };
  int*      bucket_cnt  = (int*)alloc(256 * 4);
  int*      bucket_offs = (int*)alloc(257 * 4);
  int*      gcursor     = (int*)alloc(256 * 4);
  int*      deg         = (int*)alloc((size_t)n * 4);
  int*      offs        = (int*)alloc((size_t)(n + 1) * 4);
  float*    dinv        = (float*)alloc((size_t)n * 4);
  int*      flag        = (int*)alloc(4);
  uint16_t* wf0         = (uint16_t*)alloc(64 * 1024);
  uint16_t* wf1         = (uint16_t*)alloc(64 * 1024);
  uint16_t* wf2         = (uint16_t*)alloc(32 * 1024);
  int2*     epk_binned  = (int2*)alloc((size_t)E * 8);
  uint32_t* epk         = (uint32_t*)alloc((size_t)E * 4);
  uint16_t* hbuf        = (uint16_t*)alloc((size_t)n * 128 * 2);  // sliced bf16 H'
  float*    abuf        = (float*)alloc((size_t)n * 128 * 4);     // sliced fp32 acts
  (void)ws_size;

  hipMemsetAsync(bucket_cnt, 0, 256 * 4, stream);

  // W split/fragment prep (independent of graph passes)
  wprep_k<128><<<32, 64, 0, stream>>>(W0, wf0);
  wprep_k<128><<<32, 64, 0, stream>>>(W1, wf1);
  wprep_k<64><<<16, 64, 0, stream>>>(W2, wf2);

  detect_k<<<1, 64, 0, stream>>>((const int*)ei, flag);
  passA_k<<<512, 256, 0, stream>>>(ei, flag, bucket_cnt, E, NB);
  bscan_k<<<1, 256, 0, stream>>>(bucket_cnt, bucket_offs, gcursor, NB);
  passB_k<<<(E + 4095) / 4096, 256, 0, stream>>>(ei, flag, gcursor, epk_binned, E, NB);
  passC0_k<<<NB, 256, 0, stream>>>(epk_binned, bucket_offs, deg, offs, n, NB);
  dinv_k<<<(n + 255) / 256, 256, 0, stream>>>(deg, dinv, n);
  passC_k<<<NB, 256, 0, stream>>>(epk_binned, bucket_offs, offs, epk);

  const int gemm_blocks = (n + 127) / 128;
  const int agg128_blocks = 4 * ((n + 31) / 32);
  const int ng = (n + 31) >> 5, nq = (ng + 3) >> 2;
  const int agg64_blocks = 8 * nq;

  // Layer 0 (dense x input)
  gemm_k<128, false><<<gemm_blocks, 256, 0, stream>>>(x, wf0, dinv, hbuf, n);
  agg128s_k<<<agg128_blocks, 256, 0, stream>>>((const uint32_t*)hbuf, offs, epk, b0, abuf, 1, n);
  // Layer 1 (sliced activations)
  gemm_k<128, true><<<gemm_blocks, 256, 0, stream>>>(abuf, wf1, dinv, hbuf, n);
  agg128s_k<<<agg128_blocks, 256, 0, stream>>>((const uint32_t*)hbuf, offs, epk, b1, abuf, 1, n);
  // Layer 2 (no relu) -> d_out dense fp32
  gemm_k<64, true><<<gemm_blocks, 256, 0, stream>>>(abuf, wf2, dinv, hbuf, n);
  agg64s_k<<<agg64_blocks, 256, 0, stream>>>((const uint32_t*)hbuf, offs, epk, b2, out, n);
}